// Round 1
// 835.510 us; speedup vs baseline: 1.1304x; 1.1304x over previous
//
#include <hip/hip_runtime.h>

#define B_SZ    16384
#define T_STEPS 3
#define D_IN    2752
#define H_SZ    256
#define O_SZ    100
#define LDA     (T_STEPS * D_IN)   // 8256 floats, dvs row stride per batch row

typedef short bf16x8 __attribute__((ext_vector_type(8)));   // 8 bf16 = 4 VGPRs
typedef float f32x4  __attribute__((ext_vector_type(4)));

__device__ __forceinline__ unsigned short f2bf(float x) {
  union { float f; unsigned int u; } v; v.f = x;
  unsigned int r = v.u + 0x7FFFu + ((v.u >> 16) & 1u);   // RNE
  return (unsigned short)(r >> 16);
}

// async global->LDS, 16B per lane, dest = wave-uniform base + lane*16
__device__ __forceinline__ void gload_lds16(const void* g, void* l) {
  __builtin_amdgcn_global_load_lds(
      (const __attribute__((address_space(1))) unsigned int*)g,
      (__attribute__((address_space(3))) unsigned int*)l, 16, 0, 0);
}

// ---------------------------------------------------------------------------
// W1 fp32 -> bf16 (layout preserved: [256][2752], k contiguous)
// ---------------------------------------------------------------------------
__global__ void cvt_w1_kernel(const float* __restrict__ W1,
                              unsigned short* __restrict__ W1bf) {
  int i = (blockIdx.x * 256 + threadIdx.x) * 4;
  float4 v = *(const float4*)(W1 + i);
  unsigned short o[4] = {f2bf(v.x), f2bf(v.y), f2bf(v.z), f2bf(v.w)};
  *(uint2*)(W1bf + i) = *(uint2*)o;
}

// ---------------------------------------------------------------------------
// GEMM1 v2 (bf16 MFMA, 2-phase double-buffered pipeline):
//   Hout[(t*B+b), n] = dot(dvs[b,t,:], W1[n,:]) + b1[n]
// BM=64, BN=256 (full N: A read exactly once), BK=32, 256 thr = 4 waves.
// B tile: global_load_lds w=16 into LINEAR LDS [256][32] bf16; read-side
//   8-way bank conflict (64B row stride) fixed by both-sides XOR chunk
//   swizzle: chunk' = chunk ^ ((row>>1)&3)  (source-permuted + same on read).
// A tile: reg-staged fp32->bf16 (f2bf), issued one iter ahead, converted
//   AFTER the MFMA phase so HBM latency hides under compute.
// One __syncthreads per K-step; its vmcnt(0) only drains B-loads issued a
// full iteration earlier (L2-hot). Bitwise-identical math to v1.
// ---------------------------------------------------------------------------
#define BM 64
#define BN 256
#define BK 32
#define NT (D_IN / BK)   // 86
#define LDK 40           // BK + 8 pad, ushorts (A tile only)

__device__ __forceinline__ void stage_B(const unsigned short* __restrict__ W1bf,
                                        unsigned short (*Bbuf)[BK],  // [256][32]
                                        int k0, int tid) {
  const int lane = tid & 63, w = tid >> 6;
#pragma unroll
  for (int q = 0; q < 4; ++q) {
    int g = (w * 4 + q) * 64 + lane;        // global 16B-chunk id in tile
    int r = g >> 2, c = g & 3;              // row, chunk-in-row (64B rows)
    int cp = c ^ ((r >> 1) & 3);            // fetch the swizzled source chunk
    const unsigned short* src = W1bf + (size_t)r * D_IN + k0 + cp * 8;
    gload_lds16(src, &Bbuf[(w * 4 + q) * 16][0]);   // uniform base, +lane*16
  }
}

__global__ __launch_bounds__(256, 3) void gemm1_mfma_kernel(
    const float* __restrict__ dvs, const unsigned short* __restrict__ W1bf,
    const float* __restrict__ b1, float* __restrict__ Hout) {
  __shared__ __attribute__((aligned(16))) unsigned short Ab[2][BM][LDK]; // 10240 B
  __shared__ __attribute__((aligned(16))) unsigned short Bb[2][BN][BK];  // 32768 B

  const int r0   = blockIdx.x * BM;        // output row (t*B+b)
  const int t    = r0 >> 14;
  const int brow = r0 & (B_SZ - 1);
  const float* Abase = dvs + (size_t)brow * LDA + t * D_IN;

  const int tid  = threadIdx.x;
  const int lane = tid & 63, wv = tid >> 6;
  const int wn0  = wv * 64;                // wave's n offset
  const int lrow = lane & 15;              // fragment row/col within 16
  const int kgrp = lane >> 4;              // 0..3 -> k-offset kgrp*8
  const int pidx = kgrp ^ ((lrow >> 1) & 3);   // B read swizzle (indep of n)

  // A staging map: thread -> (row = tid>>2, kq = (tid&3)*8), 8 floats
  const int s_row = tid >> 2;
  const int s_kq  = (tid & 3) << 3;
  const float* ap0 = Abase + (size_t)s_row * LDA + s_kq;

  f32x4 acc[4][4] = {};

  // ---- prologue: stage tile 0 into buffer 0 ----
  {
    float4 a0 = *(const float4*)(ap0);
    float4 a1 = *(const float4*)(ap0 + 4);
    stage_B(W1bf, Bb[0], 0, tid);
    unsigned short a8[8] = {f2bf(a0.x), f2bf(a0.y), f2bf(a0.z), f2bf(a0.w),
                            f2bf(a1.x), f2bf(a1.y), f2bf(a1.z), f2bf(a1.w)};
    *(uint4*)&Ab[0][s_row][s_kq] = *(uint4*)a8;
  }
  __syncthreads();   // drains B(0) gloads (vmcnt 0) + A lds writes

  int cur = 0;
  for (int k = 0; k < NT; ++k) {
    const bool pf = (k + 1 < NT);
    float4 a0n, a1n;
    if (pf) {                               // issue next tile's loads FIRST
      const int k0n = (k + 1) * BK;
      a0n = *(const float4*)(ap0 + k0n);
      a1n = *(const float4*)(ap0 + k0n + 4);
      stage_B(W1bf, Bb[cur ^ 1], k0n, tid);
    }

    // ---- MFMA phase on buffer `cur` (overlaps outstanding loads) ----
    {
      const unsigned short (*Ac)[LDK] = Ab[cur];
      const unsigned short (*Bc)[BK]  = Bb[cur];
      bf16x8 af[4], bfr[4];
#pragma unroll
      for (int m = 0; m < 4; m++)
        af[m] = *(const bf16x8*)&Ac[m * 16 + lrow][kgrp * 8];
#pragma unroll
      for (int n = 0; n < 4; n++)
        bfr[n] = *(const bf16x8*)&Bc[wn0 + n * 16 + lrow][pidx * 8];
#pragma unroll
      for (int m = 0; m < 4; m++)
#pragma unroll
        for (int n = 0; n < 4; n++)
          acc[m][n] = __builtin_amdgcn_mfma_f32_16x16x32_bf16(
              af[m], bfr[n], acc[m][n], 0, 0, 0);
    }

    if (pf) {                               // consume A regs late (latency hidden)
      unsigned short a8[8] = {f2bf(a0n.x), f2bf(a0n.y), f2bf(a0n.z), f2bf(a0n.w),
                              f2bf(a1n.x), f2bf(a1n.y), f2bf(a1n.z), f2bf(a1n.w)};
      *(uint4*)&Ab[cur ^ 1][s_row][s_kq] = *(uint4*)a8;
    }
    __syncthreads();   // one barrier/iter: drains B(k+1) (issued a full iter ago)
    cur ^= 1;
  }

  // epilogue: C layout col = lane&15, row = (lane>>4)*4 + reg  (unchanged)
#pragma unroll
  for (int m = 0; m < 4; m++) {
    int gm = r0 + m * 16 + kgrp * 4;
#pragma unroll
    for (int n = 0; n < 4; n++) {
      int gn = wn0 + n * 16 + lrow;
      float bias = b1[gn];
#pragma unroll
      for (int r = 0; r < 4; r++)
        Hout[(size_t)(gm + r) * H_SZ + gn] = acc[m][n][r] + bias;
    }
  }
}

// ---------------------------------------------------------------------------
// Tiled transpose: out[c*rows + r] = in[r*cols + c]
// ---------------------------------------------------------------------------
__global__ void transpose_kernel(const float* __restrict__ in,
                                 float* __restrict__ out, int rows, int cols) {
  __shared__ float tile[32][33];
  int bc = blockIdx.x * 32, br = blockIdx.y * 32;
  int tx = threadIdx.x, ty = threadIdx.y;   // 32 x 8
  for (int j = 0; j < 32; j += 8) {
    int r = br + ty + j, c = bc + tx;
    if (r < rows && c < cols) tile[ty + j][tx] = in[(size_t)r * cols + c];
  }
  __syncthreads();
  for (int j = 0; j < 32; j += 8) {
    int c = bc + ty + j, r = br + tx;
    if (c < cols && r < rows) out[(size_t)c * rows + r] = tile[tx][ty + j];
  }
}

// ---------------------------------------------------------------------------
// Recurrent LIF chain v3: one WAVE per 2 batch rows (was 8) -> 4x shorter
// serial chain, 32 waves/CU. No LDS, no barriers. Spike sets kept as 4x u64
// ballot masks (wave-uniform); layer-2 gather does 4 independent coalesced
// 256B row loads per spiking neuron (L2-resident). Layer-3 gather almost
// never executes (v2 std ~0.2 << 1.0 threshold).
// ---------------------------------------------------------------------------
__global__ __launch_bounds__(256) void recurrent2_kernel(
    const float* __restrict__ H, const float* __restrict__ W2T,
    const float* __restrict__ b2, const float* __restrict__ W3T,
    const float* __restrict__ b3, float* __restrict__ out) {
  const int tid = threadIdx.x, lane = tid & 63, wv = tid >> 6;
  const int b0 = blockIdx.x * 8 + wv * 2;

  float b2v[4];
#pragma unroll
  for (int q = 0; q < 4; q++) b2v[q] = b2[lane + 64 * q];
  const float b3a = b3[lane];
  const float b3b = (lane < O_SZ - 64) ? b3[64 + lane] : 0.f;

  for (int bi = 0; bi < 2; bi++) {
    const int b = b0 + bi;
    float v1[4] = {0.f, 0.f, 0.f, 0.f};
    float v2[4] = {0.f, 0.f, 0.f, 0.f};
    float v3a = 0.f, v3b = 0.f, s3a = 0.f, s3b = 0.f;

    for (int t = 0; t < T_STEPS; t++) {
      const float* hp = H + ((size_t)t * B_SZ + b) * H_SZ;
      unsigned long long m1[4];
      float h2[4] = {b2v[0], b2v[1], b2v[2], b2v[3]};
#pragma unroll
      for (int q = 0; q < 4; q++) {
        float h1 = hp[lane + 64 * q];
        v1[q] = 0.5f * (v1[q] + h1);
        bool s = (v1[q] >= 1.0f);
        m1[q] = __ballot(s);
        if (s) v1[q] = 0.f;
      }
#pragma unroll
      for (int q = 0; q < 4; q++) {
        unsigned long long m = m1[q];
        while (m) {
          int n = 64 * q + __builtin_ctzll(m);
          m &= m - 1;
          const float* wp = W2T + (size_t)n * H_SZ + lane;
          h2[0] += wp[0]; h2[1] += wp[64]; h2[2] += wp[128]; h2[3] += wp[192];
        }
      }
      unsigned long long m2[4];
#pragma unroll
      for (int q = 0; q < 4; q++) {
        v2[q] = 0.5f * (v2[q] + h2[q]);
        bool s = (v2[q] >= 1.0f);
        m2[q] = __ballot(s);
        if (s) v2[q] = 0.f;
      }
      float h3a = b3a, h3b = b3b;
#pragma unroll
      for (int q = 0; q < 4; q++) {
        unsigned long long m = m2[q];
        while (m) {
          int j = 64 * q + __builtin_ctzll(m);
          m &= m - 1;
          h3a += W3T[(size_t)j * O_SZ + lane];
          if (lane < O_SZ - 64) h3b += W3T[(size_t)j * O_SZ + 64 + lane];
        }
      }
      v3a = 0.5f * (v3a + h3a);
      v3b = 0.5f * (v3b + h3b);
      bool sa = (v3a >= 1.0f), sb = (v3b >= 1.0f);
      if (sa) v3a = 0.f;
      if (sb) v3b = 0.f;
      if (t == T_STEPS - 1) { s3a = sa ? 1.f : 0.f; s3b = sb ? 1.f : 0.f; }
    }
    out[(size_t)b * O_SZ + lane] = s3a;
    if (lane < O_SZ - 64) out[(size_t)b * O_SZ + 64 + lane] = s3b;
  }
}

// ---------------------------------------------------------------------------
extern "C" void kernel_launch(void* const* d_in, const int* in_sizes, int n_in,
                              void* d_out, int out_size, void* d_ws, size_t ws_size,
                              hipStream_t stream) {
  const float* dvs = (const float*)d_in[0];
  const float* W1  = (const float*)d_in[1];
  const float* b1  = (const float*)d_in[2];
  const float* W2  = (const float*)d_in[3];
  const float* b2  = (const float*)d_in[4];
  const float* W3  = (const float*)d_in[5];
  const float* b3  = (const float*)d_in[6];
  float* out = (float*)d_out;

  char* ws = (char*)d_ws;
  float* Hbuf = (float*)ws;                                  // 50,331,648 B
  float* W2T  = (float*)(ws + (size_t)T_STEPS * B_SZ * H_SZ * 4);
  float* W3T  = W2T + H_SZ * H_SZ;                           // [j][o], 256x100
  unsigned short* W1bf = (unsigned short*)(W3T + H_SZ * O_SZ);

  dim3 tb(32, 8);
  hipLaunchKernelGGL(cvt_w1_kernel, dim3((H_SZ * D_IN) / 1024), dim3(256),
                     0, stream, W1, W1bf);
  hipLaunchKernelGGL(transpose_kernel, dim3(8, 8), tb, 0, stream, W2, W2T, H_SZ, H_SZ);
  hipLaunchKernelGGL(transpose_kernel, dim3(8, 4), tb, 0, stream, W3, W3T, O_SZ, H_SZ);
  hipLaunchKernelGGL(gemm1_mfma_kernel, dim3((T_STEPS * B_SZ) / BM), dim3(256),
                     0, stream, dvs, W1bf, b1, Hbuf);
  hipLaunchKernelGGL(recurrent2_kernel, dim3(B_SZ / 8), dim3(256), 0, stream,
                     Hbuf, W2T, b2, W3T, b3, out);
}

// Round 2
// 828.494 us; speedup vs baseline: 1.1400x; 1.0085x over previous
//
#include <hip/hip_runtime.h>

#define B_SZ    16384
#define T_STEPS 3
#define D_IN    2752
#define H_SZ    256
#define O_SZ    100
#define LDA     (T_STEPS * D_IN)   // 8256 floats, dvs row stride per batch row

typedef short bf16x8 __attribute__((ext_vector_type(8)));   // 8 bf16 = 4 VGPRs
typedef float f32x4  __attribute__((ext_vector_type(4)));

__device__ __forceinline__ unsigned short f2bf(float x) {
  union { float f; unsigned int u; } v; v.f = x;
  unsigned int r = v.u + 0x7FFFu + ((v.u >> 16) & 1u);   // RNE
  return (unsigned short)(r >> 16);
}

// async global->LDS, 16B per lane, dest = wave-uniform base + lane*16
__device__ __forceinline__ void gload_lds16(const void* g, void* l) {
  __builtin_amdgcn_global_load_lds(
      (const __attribute__((address_space(1))) unsigned int*)g,
      (__attribute__((address_space(3))) unsigned int*)l, 16, 0, 0);
}

// ---------------------------------------------------------------------------
// W1 fp32 -> bf16 (layout preserved: [256][2752], k contiguous)
// ---------------------------------------------------------------------------
__global__ void cvt_w1_kernel(const float* __restrict__ W1,
                              unsigned short* __restrict__ W1bf) {
  int i = (blockIdx.x * 256 + threadIdx.x) * 4;
  float4 v = *(const float4*)(W1 + i);
  unsigned short o[4] = {f2bf(v.x), f2bf(v.y), f2bf(v.z), f2bf(v.w)};
  *(uint2*)(W1bf + i) = *(uint2*)o;
}

// ---------------------------------------------------------------------------
// GEMM1 v3 (bf16 MFMA, counted-vmcnt pipeline — T4):
//   Hout[(t*B+b), n] = dot(dvs[b,t,:], W1[n,:]) + b1[n]
// BM=64, BN=256 (full N: A read exactly once), BK=32, 256 thr = 4 waves.
// KEY STRUCTURAL FACT: B staging is WAVE-LOCAL (wave w stages and reads
// exactly LDS rows [64w,64w+64)), so B needs no cross-wave barrier — only
// its own wave's vmcnt. The barrier only orders the 5KB A tile (lgkmcnt).
// Main loop therefore uses raw s_barrier + s_waitcnt vmcnt(2) lgkmcnt(0):
// the 2 outstanding vm ops are the distance-2 A prefetch (never drained in
// the loop, T4 "never 0"). Issue order pinned by sched_barrier(0) so the
// vm-queue composition is static: [4x B gload_lds older | 2x A flat newer].
// Last two K-steps peeled with full-drain __syncthreads (tail counts differ).
// Bitwise-identical math to v2 (same f2bf, same MFMA order).
// ---------------------------------------------------------------------------
#define BM 64
#define BN 256
#define BK 32
#define NT (D_IN / BK)   // 86
#define LDK 40           // BK + 8 pad, ushorts (A tile only)

__device__ __forceinline__ void stage_B(const unsigned short* __restrict__ W1bf,
                                        unsigned short (*Bbuf)[BK],  // [256][32]
                                        int k0, int tid) {
  const int lane = tid & 63, w = tid >> 6;
#pragma unroll
  for (int q = 0; q < 4; ++q) {
    int g = (w * 4 + q) * 64 + lane;        // global 16B-chunk id in tile
    int r = g >> 2, c = g & 3;              // row, chunk-in-row (64B rows)
    int cp = c ^ ((r >> 1) & 3);            // fetch the swizzled source chunk
    const unsigned short* src = W1bf + (size_t)r * D_IN + k0 + cp * 8;
    gload_lds16(src, &Bbuf[(w * 4 + q) * 16][0]);   // uniform base, +lane*16
  }
}

__device__ __forceinline__ void writeA(unsigned short (*dst)[LDK], int s_row,
                                       int s_kq, float4 x, float4 y) {
  unsigned short a8[8] = {f2bf(x.x), f2bf(x.y), f2bf(x.z), f2bf(x.w),
                          f2bf(y.x), f2bf(y.y), f2bf(y.z), f2bf(y.w)};
  *(uint4*)&dst[s_row][s_kq] = *(uint4*)a8;
}

__device__ __forceinline__ void mfma_phase(
    const unsigned short (*Ac)[LDK], const unsigned short (*Bc)[BK],
    f32x4 (&acc)[4][4], int lrow, int kgrp, int wn0, int pidx) {
  bf16x8 af[4], bfr[4];
#pragma unroll
  for (int m = 0; m < 4; m++)
    af[m] = *(const bf16x8*)&Ac[m * 16 + lrow][kgrp * 8];
#pragma unroll
  for (int n = 0; n < 4; n++)
    bfr[n] = *(const bf16x8*)&Bc[wn0 + n * 16 + lrow][pidx * 8];
#pragma unroll
  for (int m = 0; m < 4; m++)
#pragma unroll
    for (int n = 0; n < 4; n++)
      acc[m][n] = __builtin_amdgcn_mfma_f32_16x16x32_bf16(
          af[m], bfr[n], acc[m][n], 0, 0, 0);
}

__global__ __launch_bounds__(256, 3) void gemm1_mfma_kernel(
    const float* __restrict__ dvs, const unsigned short* __restrict__ W1bf,
    const float* __restrict__ b1, float* __restrict__ Hout) {
  __shared__ __attribute__((aligned(16))) unsigned short Ab[2][BM][LDK]; // 10240 B
  __shared__ __attribute__((aligned(16))) unsigned short Bb[2][BN][BK];  // 32768 B

  const int r0   = blockIdx.x * BM;        // output row (t*B+b)
  const int t    = r0 >> 14;
  const int brow = r0 & (B_SZ - 1);
  const float* Abase = dvs + (size_t)brow * LDA + t * D_IN;

  const int tid  = threadIdx.x;
  const int lane = tid & 63, wv = tid >> 6;
  const int wn0  = wv * 64;                // wave's n offset
  const int lrow = lane & 15;              // fragment row/col within 16
  const int kgrp = lane >> 4;              // 0..3 -> k-offset kgrp*8
  const int pidx = kgrp ^ ((lrow >> 1) & 3);   // B read swizzle (indep of n)

  // A staging map: thread -> (row = tid>>2, kq = (tid&3)*8), 8 floats
  const int s_row = tid >> 2;
  const int s_kq  = (tid & 3) << 3;
  const float* ap0 = Abase + (size_t)s_row * LDA + s_kq;

  f32x4 acc[4][4] = {};

  // ---- prologue: B(0)->buf0, A(0)->LDS, A(1) in flight; full drain once ----
  stage_B(W1bf, Bb[0], 0, tid);
  float4 t0 = *(const float4*)(ap0);
  float4 t1 = *(const float4*)(ap0 + 4);
  float4 xA = *(const float4*)(ap0 + BK);        // A(1)
  float4 yA = *(const float4*)(ap0 + BK + 4);
  writeA(Ab[0], s_row, s_kq, t0, t1);
  __syncthreads();
  float4 xB, yB;

  // ---- main loop: k = 0..NT-3, unrolled x2 for static A-reg double-buffer ----
  for (int k = 0; k < NT - 2; k += 2) {
    // ===== step k (compute buf0) =====
    stage_B(W1bf, Bb[1], (k + 1) * BK, tid);     // 4x gload_lds (vm, oldest)
    __builtin_amdgcn_sched_barrier(0);
    xB = *(const float4*)(ap0 + (k + 2) * BK);   // A(k+2), 2x flat (vm, newest)
    yB = *(const float4*)(ap0 + (k + 2) * BK + 4);
    __builtin_amdgcn_sched_barrier(0);
    mfma_phase(Ab[0], Bb[0], acc, lrow, kgrp, wn0, pidx);
    writeA(Ab[1], s_row, s_kq, xA, yA);          // A(k+1); auto-wait vmcnt(6)
    asm volatile("s_waitcnt vmcnt(2) lgkmcnt(0)" ::: "memory"); // B(k+1) done,
    __builtin_amdgcn_sched_barrier(0);           // A(k+2) still in flight
    __builtin_amdgcn_s_barrier();
    __builtin_amdgcn_sched_barrier(0);

    // ===== step k+1 (compute buf1) =====
    stage_B(W1bf, Bb[0], (k + 2) * BK, tid);
    __builtin_amdgcn_sched_barrier(0);
    xA = *(const float4*)(ap0 + (k + 3) * BK);   // A(k+3)
    yA = *(const float4*)(ap0 + (k + 3) * BK + 4);
    __builtin_amdgcn_sched_barrier(0);
    mfma_phase(Ab[1], Bb[1], acc, lrow, kgrp, wn0, pidx);
    writeA(Ab[0], s_row, s_kq, xB, yB);          // A(k+2)
    asm volatile("s_waitcnt vmcnt(2) lgkmcnt(0)" ::: "memory");
    __builtin_amdgcn_sched_barrier(0);
    __builtin_amdgcn_s_barrier();
    __builtin_amdgcn_sched_barrier(0);
  }

  // ---- tail: k = NT-2 (buf0) and k = NT-1 (buf1), full-drain semantics ----
  stage_B(W1bf, Bb[1], (NT - 1) * BK, tid);
  mfma_phase(Ab[0], Bb[0], acc, lrow, kgrp, wn0, pidx);
  writeA(Ab[1], s_row, s_kq, xA, yA);            // A(NT-1)
  __syncthreads();                               // drains B(NT-1) + ds_writes
  mfma_phase(Ab[1], Bb[1], acc, lrow, kgrp, wn0, pidx);

  // epilogue: C layout col = lane&15, row = (lane>>4)*4 + reg  (unchanged)
#pragma unroll
  for (int m = 0; m < 4; m++) {
    int gm = r0 + m * 16 + kgrp * 4;
#pragma unroll
    for (int n = 0; n < 4; n++) {
      int gn = wn0 + n * 16 + lrow;
      float bias = b1[gn];
#pragma unroll
      for (int r = 0; r < 4; r++)
        Hout[(size_t)(gm + r) * H_SZ + gn] = acc[m][n][r] + bias;
    }
  }
}

// ---------------------------------------------------------------------------
// Tiled transpose: out[c*rows + r] = in[r*cols + c]
// ---------------------------------------------------------------------------
__global__ void transpose_kernel(const float* __restrict__ in,
                                 float* __restrict__ out, int rows, int cols) {
  __shared__ float tile[32][33];
  int bc = blockIdx.x * 32, br = blockIdx.y * 32;
  int tx = threadIdx.x, ty = threadIdx.y;   // 32 x 8
  for (int j = 0; j < 32; j += 8) {
    int r = br + ty + j, c = bc + tx;
    if (r < rows && c < cols) tile[ty + j][tx] = in[(size_t)r * cols + c];
  }
  __syncthreads();
  for (int j = 0; j < 32; j += 8) {
    int c = bc + ty + j, r = br + tx;
    if (c < cols && r < rows) out[(size_t)c * rows + r] = tile[tx][ty + j];
  }
}

// ---------------------------------------------------------------------------
// Recurrent LIF chain v3: one WAVE per 2 batch rows. No LDS, no barriers.
// Spike sets kept as 4x u64 ballot masks (wave-uniform); layer-2 gather does
// 4 independent coalesced 256B row loads per spiking neuron (L2-resident).
// Layer-3 gather almost never executes (v2 std ~0.2 << 1.0 threshold).
// ---------------------------------------------------------------------------
__global__ __launch_bounds__(256) void recurrent2_kernel(
    const float* __restrict__ H, const float* __restrict__ W2T,
    const float* __restrict__ b2, const float* __restrict__ W3T,
    const float* __restrict__ b3, float* __restrict__ out) {
  const int tid = threadIdx.x, lane = tid & 63, wv = tid >> 6;
  const int b0 = blockIdx.x * 8 + wv * 2;

  float b2v[4];
#pragma unroll
  for (int q = 0; q < 4; q++) b2v[q] = b2[lane + 64 * q];
  const float b3a = b3[lane];
  const float b3b = (lane < O_SZ - 64) ? b3[64 + lane] : 0.f;

  for (int bi = 0; bi < 2; bi++) {
    const int b = b0 + bi;
    float v1[4] = {0.f, 0.f, 0.f, 0.f};
    float v2[4] = {0.f, 0.f, 0.f, 0.f};
    float v3a = 0.f, v3b = 0.f, s3a = 0.f, s3b = 0.f;

    for (int t = 0; t < T_STEPS; t++) {
      const float* hp = H + ((size_t)t * B_SZ + b) * H_SZ;
      unsigned long long m1[4];
      float h2[4] = {b2v[0], b2v[1], b2v[2], b2v[3]};
#pragma unroll
      for (int q = 0; q < 4; q++) {
        float h1 = hp[lane + 64 * q];
        v1[q] = 0.5f * (v1[q] + h1);
        bool s = (v1[q] >= 1.0f);
        m1[q] = __ballot(s);
        if (s) v1[q] = 0.f;
      }
#pragma unroll
      for (int q = 0; q < 4; q++) {
        unsigned long long m = m1[q];
        while (m) {
          int n = 64 * q + __builtin_ctzll(m);
          m &= m - 1;
          const float* wp = W2T + (size_t)n * H_SZ + lane;
          h2[0] += wp[0]; h2[1] += wp[64]; h2[2] += wp[128]; h2[3] += wp[192];
        }
      }
      unsigned long long m2[4];
#pragma unroll
      for (int q = 0; q < 4; q++) {
        v2[q] = 0.5f * (v2[q] + h2[q]);
        bool s = (v2[q] >= 1.0f);
        m2[q] = __ballot(s);
        if (s) v2[q] = 0.f;
      }
      float h3a = b3a, h3b = b3b;
#pragma unroll
      for (int q = 0; q < 4; q++) {
        unsigned long long m = m2[q];
        while (m) {
          int j = 64 * q + __builtin_ctzll(m);
          m &= m - 1;
          h3a += W3T[(size_t)j * O_SZ + lane];
          if (lane < O_SZ - 64) h3b += W3T[(size_t)j * O_SZ + 64 + lane];
        }
      }
      v3a = 0.5f * (v3a + h3a);
      v3b = 0.5f * (v3b + h3b);
      bool sa = (v3a >= 1.0f), sb = (v3b >= 1.0f);
      if (sa) v3a = 0.f;
      if (sb) v3b = 0.f;
      if (t == T_STEPS - 1) { s3a = sa ? 1.f : 0.f; s3b = sb ? 1.f : 0.f; }
    }
    out[(size_t)b * O_SZ + lane] = s3a;
    if (lane < O_SZ - 64) out[(size_t)b * O_SZ + 64 + lane] = s3b;
  }
}

// ---------------------------------------------------------------------------
extern "C" void kernel_launch(void* const* d_in, const int* in_sizes, int n_in,
                              void* d_out, int out_size, void* d_ws, size_t ws_size,
                              hipStream_t stream) {
  const float* dvs = (const float*)d_in[0];
  const float* W1  = (const float*)d_in[1];
  const float* b1  = (const float*)d_in[2];
  const float* W2  = (const float*)d_in[3];
  const float* b2  = (const float*)d_in[4];
  const float* W3  = (const float*)d_in[5];
  const float* b3  = (const float*)d_in[6];
  float* out = (float*)d_out;

  char* ws = (char*)d_ws;
  float* Hbuf = (float*)ws;                                  // 50,331,648 B
  float* W2T  = (float*)(ws + (size_t)T_STEPS * B_SZ * H_SZ * 4);
  float* W3T  = W2T + H_SZ * H_SZ;                           // [j][o], 256x100
  unsigned short* W1bf = (unsigned short*)(W3T + H_SZ * O_SZ);

  dim3 tb(32, 8);
  hipLaunchKernelGGL(cvt_w1_kernel, dim3((H_SZ * D_IN) / 1024), dim3(256),
                     0, stream, W1, W1bf);
  hipLaunchKernelGGL(transpose_kernel, dim3(8, 8), tb, 0, stream, W2, W2T, H_SZ, H_SZ);
  hipLaunchKernelGGL(transpose_kernel, dim3(8, 4), tb, 0, stream, W3, W3T, O_SZ, H_SZ);
  hipLaunchKernelGGL(gemm1_mfma_kernel, dim3((T_STEPS * B_SZ) / BM), dim3(256),
                     0, stream, dvs, W1bf, b1, Hbuf);
  hipLaunchKernelGGL(recurrent2_kernel, dim3(B_SZ / 8), dim3(256), 0, stream,
                     Hbuf, W2T, b2, W3T, b3, out);
}